// Round 3
// baseline (487.787 us; speedup 1.0000x reference)
//
#include <hip/hip_runtime.h>

// LIF neuron scan: x [T=16, B=32, C=128, H=32, W=32] fp32 -> spikes same shape.
//   u1   = mem*0.5 + x*0.5 ; spk = (u1 > 1) ; mem' = spk ? 0 : u1
// Sequential only in T; all B*C*H*W positions independent.
//
// R1 post-mortem: loop-per-t version was LATENCY-bound (VALUBusy 4%, HBM 29%,
// VGPR=28 => ~1 load in flight/wave). Fix: hoist the entire T=16 column into
// registers (16 independent global_load_dwordx4 back-to-back, 16 KB in flight
// per wave), then scan + nontemporal stores.
// R2: __builtin_nontemporal_store requires a NATIVE clang vector type, not
// HIP's float4 class -> use ext_vector_type(4).

constexpr int   T_STEPS     = 16;
constexpr float DECAY       = 0.5f;   // 1 - 1/tau, tau=2
constexpr float INPUT_SCALE = 0.5f;   // 1/tau
constexpr float THRESH      = 1.0f;

typedef float floatx4 __attribute__((ext_vector_type(4)));

__global__ __launch_bounds__(256) void lif_scan_kernel(
    const float* __restrict__ x,
    float*       __restrict__ out,
    int n_per_t)                      // elements per time slice (4,194,304)
{
    const int i = (blockIdx.x * blockDim.x + threadIdx.x) * 4;
    if (i >= n_per_t) return;

    // Phase 1: issue ALL 16 loads before any use -> 16 outstanding
    // global_load_dwordx4 per lane (16 KB in flight per wave).
    floatx4 v[T_STEPS];
    #pragma unroll
    for (int t = 0; t < T_STEPS; ++t) {
        const size_t off = (size_t)t * (size_t)n_per_t + (size_t)i;
        v[t] = *reinterpret_cast<const floatx4*>(x + off);
    }

    // Phase 2: sequential scan; compiler waits vmcnt(15-t) per use, so the
    // tail loads still fly while early steps compute. Nontemporal stores:
    // spikes are write-once, never re-read -> keep L3 free for x.
    floatx4 mem = (floatx4)(0.f);
    #pragma unroll
    for (int t = 0; t < T_STEPS; ++t) {
        floatx4 u, s;
        #pragma unroll
        for (int k = 0; k < 4; ++k) {
            u[k]   = mem[k] * DECAY + v[t][k] * INPUT_SCALE;
            s[k]   = (u[k] > THRESH) ? 1.0f : 0.0f;
            mem[k] = (u[k] > THRESH) ? 0.0f : u[k];
        }
        const size_t off = (size_t)t * (size_t)n_per_t + (size_t)i;
        __builtin_nontemporal_store(s, reinterpret_cast<floatx4*>(out + off));
    }
}

extern "C" void kernel_launch(void* const* d_in, const int* in_sizes, int n_in,
                              void* d_out, int out_size, void* d_ws, size_t ws_size,
                              hipStream_t stream) {
    const float* x   = (const float*)d_in[0];
    float*       out = (float*)d_out;

    const int total   = in_sizes[0];          // T * B * C * H * W
    const int n_per_t = total / T_STEPS;      // 4,194,304

    const int threads = 256;
    const int n_vec   = n_per_t / 4;          // one thread per float4 column
    const int blocks  = (n_vec + threads - 1) / threads;

    lif_scan_kernel<<<blocks, threads, 0, stream>>>(x, out, n_per_t);
}

// Round 4
// 452.090 us; speedup vs baseline: 1.0790x; 1.0790x over previous
//
#include <hip/hip_runtime.h>

// LIF neuron scan: x [T=16, B=32, C=128, H=32, W=32] fp32 -> spikes same shape.
//   u1   = mem*0.5 + x*0.5 ; spk = (u1 > 1) ; mem' = spk ? 0 : u1
// Sequential only in T; all B*C*H*W positions independent.
//
// R1: loop version latency-bound (VALUBusy 4%, HBM 29%, VGPR=28).
// R3 post-mortem: compiler SANK the hoisted loads (VGPR=32) -> load/store
// interleave; vmcnt is in-issue-order so each load-use waits on the previous
// store's completion -> serialized round trips. Fix: pin the 16-load prologue
// with sched_barrier(0) so all loads are in flight before any store issues.
// Stores are then younger than every load and never block a load-use wait.

constexpr int   T_STEPS     = 16;
constexpr float DECAY       = 0.5f;   // 1 - 1/tau, tau=2
constexpr float INPUT_SCALE = 0.5f;   // 1/tau
constexpr float THRESH      = 1.0f;

typedef float floatx4 __attribute__((ext_vector_type(4)));

__global__ __launch_bounds__(256, 4) void lif_scan_kernel(
    const float* __restrict__ x,
    float*       __restrict__ out,
    int n_per_t)                      // elements per time slice (4,194,304)
{
    const int i = (blockIdx.x * blockDim.x + threadIdx.x) * 4;
    if (i >= n_per_t) return;

    // Phase 1: issue ALL 16 global_load_dwordx4 back-to-back (16 KB in
    // flight per wave). sched_barrier(0) forbids the scheduler from sinking
    // any of them below this point.
    floatx4 v[T_STEPS];
    #pragma unroll
    for (int t = 0; t < T_STEPS; ++t) {
        const size_t off = (size_t)t * (size_t)n_per_t + (size_t)i;
        v[t] = *reinterpret_cast<const floatx4*>(x + off);
    }
    __builtin_amdgcn_sched_barrier(0);

    // Phase 2: sequential scan. Load t is consumed at vmcnt(15-t)+stores;
    // stores are all younger than all loads, so no load-use ever waits on a
    // store. Store each spike slice as soon as it's computed.
    floatx4 mem = (floatx4)(0.f);
    #pragma unroll
    for (int t = 0; t < T_STEPS; ++t) {
        floatx4 u, s;
        #pragma unroll
        for (int k = 0; k < 4; ++k) {
            u[k]   = mem[k] * DECAY + v[t][k] * INPUT_SCALE;
            s[k]   = (u[k] > THRESH) ? 1.0f : 0.0f;
            mem[k] = (u[k] > THRESH) ? 0.0f : u[k];
        }
        const size_t off = (size_t)t * (size_t)n_per_t + (size_t)i;
        *reinterpret_cast<floatx4*>(out + off) = s;
    }
}

extern "C" void kernel_launch(void* const* d_in, const int* in_sizes, int n_in,
                              void* d_out, int out_size, void* d_ws, size_t ws_size,
                              hipStream_t stream) {
    const float* x   = (const float*)d_in[0];
    float*       out = (float*)d_out;

    const int total   = in_sizes[0];          // T * B * C * H * W
    const int n_per_t = total / T_STEPS;      // 4,194,304

    const int threads = 256;
    const int n_vec   = n_per_t / 4;          // one thread per float4 column
    const int blocks  = (n_vec + threads - 1) / threads;

    lif_scan_kernel<<<blocks, threads, 0, stream>>>(x, out, n_per_t);
}

// Round 6
// 428.320 us; speedup vs baseline: 1.1388x; 1.0555x over previous
//
#include <hip/hip_runtime.h>

// LIF neuron scan: x [T=16, B=32, C=128, H=32, W=32] fp32 -> spikes same shape.
//   u1   = mem*0.5 + x*0.5 ; spk = (u1 > 1) ; mem' = spk ? 0 : u1
// Sequential only in T; all B*C*H*W positions independent.
//
// History:
//  R1: 1 column/thread  — latency-bound: 2 KB moved per serialized round trip
//      (load + store-ack chained through vmcnt(0)); 2.3 TB/s, VALUBusy 4%.
//  R3/R4: register hoist (+sched_barrier) — compiler sank the loads, no change.
//  R5: inline-asm hoist — ALU uses hoisted above the waitcnt asm => WRONG DATA.
//  R6 (this): 4 independent block-strided columns per thread. The 4 loads per
//      iteration are consumed in-iteration, so the compiler batches them
//      (no cross-iteration hoist needed): 4 KB in flight per wave per RT,
//      4x amortization, pure C++ correctness.

constexpr int   T_STEPS     = 16;
constexpr int   COLS        = 4;      // float4 columns per thread
constexpr float DECAY       = 0.5f;   // 1 - 1/tau, tau=2
constexpr float INPUT_SCALE = 0.5f;   // 1/tau
constexpr float THRESH      = 1.0f;

typedef float floatx4 __attribute__((ext_vector_type(4)));

__global__ __launch_bounds__(256) void lif_scan_kernel(
    const float* __restrict__ x,
    float*       __restrict__ out,
    int n_per_t)                      // elements per time slice (4,194,304)
{
    const int n4 = n_per_t >> 2;                       // float4s per slice
    // Block-strided columns: lane-adjacent addresses within each load inst.
    const int f4_base = blockIdx.x * (256 * COLS) + threadIdx.x;

    const floatx4* __restrict__ xin  = reinterpret_cast<const floatx4*>(x);
    floatx4*       __restrict__ outv = reinterpret_cast<floatx4*>(out);

    floatx4 mem[COLS];
    #pragma unroll
    for (int c = 0; c < COLS; ++c) mem[c] = (floatx4)(0.f);

    #pragma unroll
    for (int t = 0; t < T_STEPS; ++t) {
        const size_t slice = (size_t)t * (size_t)n4 + (size_t)f4_base;

        // 4 independent coalesced loads, batched back-to-back by the
        // scheduler (all precede their uses within this basic block).
        floatx4 v[COLS];
        #pragma unroll
        for (int c = 0; c < COLS; ++c)
            v[c] = xin[slice + c * 256];

        #pragma unroll
        for (int c = 0; c < COLS; ++c) {
            floatx4 u, s;
            #pragma unroll
            for (int k = 0; k < 4; ++k) {
                u[k]      = mem[c][k] * DECAY + v[c][k] * INPUT_SCALE;
                s[k]      = (u[k] > THRESH) ? 1.0f : 0.0f;
                mem[c][k] = (u[k] > THRESH) ? 0.0f : u[k];
            }
            outv[slice + c * 256] = s;
        }
    }
}

extern "C" void kernel_launch(void* const* d_in, const int* in_sizes, int n_in,
                              void* d_out, int out_size, void* d_ws, size_t ws_size,
                              hipStream_t stream) {
    const float* x   = (const float*)d_in[0];
    float*       out = (float*)d_out;

    const int total   = in_sizes[0];          // T * B * C * H * W
    const int n_per_t = total / T_STEPS;      // 4,194,304

    const int threads = 256;
    const int n4      = n_per_t / 4;          // 1,048,576 float4s per slice
    const int blocks  = n4 / (threads * COLS);  // 1024 blocks

    lif_scan_kernel<<<blocks, threads, 0, stream>>>(x, out, n_per_t);
}